// Round 7
// baseline (240.480 us; speedup 1.0000x reference)
//
#include <hip/hip_runtime.h>
#include <hip/hip_bf16.h>
#include <hip/hip_cooperative_groups.h>

namespace cg = cooperative_groups;

#define N_SRC 50000
#define N_DST 10000
#define KNBR  32
#define IN_F  256
#define OUT_F 128
#define LDIM  10
#define ATTN_OUT 1024
#define NB_BIG  782   // ceil(50000/64)
#define NB_SELF 157   // ceil(10000/64)
#define NB_TOT  939

using f32x4 = __attribute__((ext_vector_type(4))) float;
using s16x8 = __attribute__((ext_vector_type(8))) short;

// Output layout (floats): rst (N_DST*128) | cent_l (N_DST*10) | labels_ori[:N_DST] (N_DST*10)
#define OUT_CENT (N_DST*OUT_F)
#define OUT_LORI (N_DST*OUT_F + N_DST*LDIM)

// Workspace float offsets (shared by both paths)
#define WS_WCOMB 0                                   // 128 floats
#define WS_BN    128                                 // 32768 ushort
#define WS_BS    (128 + 16384)                       // 32768 ushort
#define WS_HSRC  (128 + 32768)                       // N_SRC*128 ushort
#define WS_SELF0 (WS_HSRC + (N_SRC*OUT_F/2))         // N_DST*128 floats
#define WS_SCORE (WS_SELF0 + N_DST*OUT_F)            // N_SRC floats (fallback path only)

__device__ __forceinline__ ushort f2bf(float x) {
  __hip_bfloat16 h = __float2bfloat16(x);
  return *reinterpret_cast<ushort*>(&h);
}

__device__ __forceinline__ void unpack8(uint4 hv, float* o) {
  o[0] = __uint_as_float(hv.x << 16);
  o[1] = __uint_as_float(hv.x & 0xffff0000u);
  o[2] = __uint_as_float(hv.y << 16);
  o[3] = __uint_as_float(hv.y & 0xffff0000u);
  o[4] = __uint_as_float(hv.z << 16);
  o[5] = __uint_as_float(hv.z & 0xffff0000u);
  o[6] = __uint_as_float(hv.w << 16);
  o[7] = __uint_as_float(hv.w & 0xffff0000u);
}

// ---------------------------------------------------------------------------
// GEMM tile (64 rows): wave = 16 rows, batched A-loads, B-frags streamed from
// the L2-resident pre-subtiled 64 KB table. NEIGH: bf16 out. SELF: fp32 out,
// pre-scaled (v*0.5 + out_bias).
// ---------------------------------------------------------------------------
template<bool NEIGH, bool SCORE>
__device__ __forceinline__ void gemm_tile(
    const float* A, const ushort* Bp, const float* bias,
    const float* out_bias, const float* w_comb, float* score_f,
    void* C, int M, int m0) {
  const int t = threadIdx.x;
  const int wv = t >> 6, ln = t & 63;
  const int dg = ln & 15, kg = ln >> 4;
  int r = m0 + wv * 16 + dg;
  r = r < M ? r : M - 1;                    // branchless clamp: loads always valid
  const float* arow = &A[(size_t)r * IN_F];

  s16x8 afr[8];
#pragma unroll
  for (int half = 0; half < 2; ++half) {
    f32x4 araw[8];
#pragma unroll
    for (int k0 = 0; k0 < 4; ++k0) {
      const f32x4* ap = (const f32x4*)&arow[(half * 4 + k0) * 32 + kg * 8];
      araw[2 * k0]     = ap[0];
      araw[2 * k0 + 1] = ap[1];
    }
#pragma unroll
    for (int k0 = 0; k0 < 4; ++k0) {
      s16x8 f;
      f[0] = (short)f2bf(araw[2*k0][0]); f[1] = (short)f2bf(araw[2*k0][1]);
      f[2] = (short)f2bf(araw[2*k0][2]); f[3] = (short)f2bf(araw[2*k0][3]);
      f[4] = (short)f2bf(araw[2*k0+1][0]); f[5] = (short)f2bf(araw[2*k0+1][1]);
      f[6] = (short)f2bf(araw[2*k0+1][2]); f[7] = (short)f2bf(araw[2*k0+1][3]);
      afr[half * 4 + k0] = f;
    }
  }

  f32x4 acc[8];
#pragma unroll
  for (int ct = 0; ct < 8; ++ct) acc[ct] = (f32x4){0.f, 0.f, 0.f, 0.f};
#pragma unroll
  for (int k0 = 0; k0 < 8; ++k0) {
    const ushort* bb = Bp + (k0 * 4 + kg) * 1024 + dg * 8;
#pragma unroll
    for (int ct = 0; ct < 8; ++ct) {
      s16x8 bfr = *reinterpret_cast<const s16x8*>(bb + ct * 128);
      acc[ct] = __builtin_amdgcn_mfma_f32_16x16x32_bf16(afr[k0], bfr, acc[ct], 0, 0, 0);
    }
  }

  // Epilogue. D layout: col = ct*16+dg, row = m0+wv*16+kg*4+e (HW-verified m89).
  float sc[4] = {0.f, 0.f, 0.f, 0.f};
#pragma unroll
  for (int ct = 0; ct < 8; ++ct) {
    int col = ct * 16 + dg;
    float bb = bias[col];
    float wc = SCORE ? w_comb[col] : 0.f;
#pragma unroll
    for (int e = 0; e < 4; ++e) {
      int rr = m0 + wv * 16 + kg * 4 + e;
      float v = acc[ct][e] + bb;
      if (SCORE) sc[e] = fmaf(fmaxf(v, 0.1f * v), wc, sc[e]);
      if (rr < M) {
        if (NEIGH) ((ushort*)C)[(size_t)rr * OUT_F + col] = f2bf(v);
        else       ((float*)C)[(size_t)rr * OUT_F + col] = v * 0.5f + out_bias[col];
      }
    }
  }
  if (SCORE) {
#pragma unroll
    for (int s = 1; s < 16; s <<= 1) {
#pragma unroll
      for (int e = 0; e < 4; ++e) sc[e] += __shfl_xor(sc[e], s);
    }
    if (dg == 0) {
#pragma unroll
      for (int e = 0; e < 4; ++e) {
        int rr = m0 + wv * 16 + kg * 4 + e;
        if (rr < M) score_f[rr] = sc[e];
      }
    }
  }
}

// ===========================================================================
// PATH A: single cooperative kernel (grid-size-agnostic via gridDim.x)
// ===========================================================================
__global__ __launch_bounds__(256, 2) void fused_all(
    const float* feat, const float* labels, const float* labels_ori,
    const float* label_rela, const float* W_neigh, const float* b_neigh,
    const float* W_self, const float* b_self, const float* W_attn,
    const float* fW, const float* eps_p, const float* out_bias,
    const int* nbr_idx, float* wsf, float* out) {
  float*  w_comb = wsf + WS_WCOMB;
  ushort* Bn     = (ushort*)(wsf + WS_BN);
  ushort* Bs     = (ushort*)(wsf + WS_BS);
  ushort* hsrc   = (ushort*)(wsf + WS_HSRC);
  float*  self0h = wsf + WS_SELF0;

  const int b = blockIdx.x;
  const int t = threadIdx.x;
  const int nblk = gridDim.x;

  // ---------------- P0: 512 virtual tasks, grid-strided ----------------
  __shared__ float red[256];
  for (int vb = b; vb < 512; vb += nblk) {
    if (vb < 128) {
      float s = 0.f;
#pragma unroll
      for (int i = 0; i < 4; ++i) {
        int o = t + i * 256;
        s += W_attn[(size_t)vb * ATTN_OUT + o] * fW[o];
      }
      red[t] = s;
      __syncthreads();
      for (int st = 128; st > 0; st >>= 1) {
        if (t < st) red[t] += red[t + st];
        __syncthreads();
      }
      if (t == 0) w_comb[vb] = red[0];
      __syncthreads();
    } else if (vb < 256) {
      int k = 2 * (vb - 128) + (t >> 7);
      int n = t & 127;
      Bn[(k >> 3) * 1024 + n * 8 + (k & 7)] = f2bf(W_neigh[(size_t)k * OUT_F + n]);
    } else if (vb < 384) {
      int k = 2 * (vb - 256) + (t >> 7);
      int n = t & 127;
      Bs[(k >> 3) * 1024 + n * 8 + (k & 7)] = f2bf(W_self[(size_t)k * OUT_F + n]);
    } else if (vb < 448) {
      int tid = (vb - 384) * 256 + t;                       // 16384 threads
      const f32x4* src = (const f32x4*)labels;
      f32x4* dst = (f32x4*)(out + OUT_CENT);
      for (int i = tid; i < N_DST * LDIM / 4; i += 16384) dst[i] = src[i];
    } else {
      int tid = (vb - 448) * 256 + t;
      const f32x4* src = (const f32x4*)labels_ori;
      f32x4* dst = (f32x4*)(out + OUT_LORI);
      for (int i = tid; i < N_DST * LDIM / 4; i += 16384) dst[i] = src[i];
    }
  }

  cg::this_grid().sync();

  // ---------------- P1: GEMM, grid-strided tiles ----------------
  for (int tile = b; tile < NB_TOT; tile += nblk) {
    if (tile < NB_BIG)
      gemm_tile<true, false>(feat, Bn, b_neigh, out_bias, nullptr, nullptr,
                             (void*)hsrc, N_SRC, tile * 64);
    else
      gemm_tile<false, false>(feat, Bs, b_self, out_bias, nullptr, nullptr,
                              (void*)self0h, N_DST, (tile - NB_BIG) * 64);
  }

  cg::this_grid().sync();

  // ---------------- P2: attention, wave per node, grid-strided ----------------
  const int wv = t >> 6, ln = t & 63;
  const int dg = ln & 15, kg = ln >> 4;
  const float eps = eps_p[0];
  const float om = 1.f - eps;

  float wcs[8];
  {
    const f32x4* wp = (const f32x4*)&w_comb[dg * 8];
    f32x4 w0 = wp[0], w1 = wp[1];
    wcs[0] = om * w0[0]; wcs[1] = om * w0[1]; wcs[2] = om * w0[2]; wcs[3] = om * w0[3];
    wcs[4] = om * w1[0]; wcs[5] = om * w1[1]; wcs[6] = om * w1[2]; wcs[7] = om * w1[3];
  }

  for (int n = b * 4 + wv; n < N_DST; n += nblk * 4) {
    float va = 0.f;
    if (dg < LDIM) {
#pragma unroll
      for (int bb = 0; bb < LDIM; ++bb)
        va += label_rela[dg * LDIM + bb] * labels[(size_t)n * LDIM + bb];
      va *= eps;
    }

    const int* irow = nbr_idx + (size_t)n * KNBR;
    float hf[8][8];
    float m[8];
#pragma unroll
    for (int j = 0; j < 8; ++j) {
      int id = irow[kg * 8 + j];
      uint4 hv = *(const uint4*)(hsrc + (size_t)id * OUT_F + dg * 8);
      unpack8(hv, hf[j]);
      float p = 0.f;
#pragma unroll
      for (int e = 0; e < 8; ++e)
        p = fmaf(fmaxf(hf[j][e], 0.1f * hf[j][e]), wcs[e], p);
      if (dg < LDIM) p = fmaf(labels[(size_t)id * LDIM + dg], va, p);
      m[j] = p;
    }
#pragma unroll
    for (int s = 1; s < 16; s <<= 1) {
#pragma unroll
      for (int j = 0; j < 8; ++j) m[j] += __shfl_xor(m[j], s);
    }
    float mx = m[0];
#pragma unroll
    for (int j = 1; j < 8; ++j) mx = fmaxf(mx, m[j]);
    mx = fmaxf(mx, __shfl_xor(mx, 16));
    mx = fmaxf(mx, __shfl_xor(mx, 32));
    float ssum = 0.f;
#pragma unroll
    for (int j = 0; j < 8; ++j) {
      m[j] = __expf(m[j] - mx);
      ssum += m[j];
    }
    ssum += __shfl_xor(ssum, 16);
    ssum += __shfl_xor(ssum, 32);
    const float scale2 = 0.5f / (ssum * (float)KNBR);

    float pn[8];
#pragma unroll
    for (int e = 0; e < 8; ++e) pn[e] = 0.f;
#pragma unroll
    for (int j = 0; j < 8; ++j) {
#pragma unroll
      for (int e = 0; e < 8; ++e) pn[e] = fmaf(m[j], hf[j][e], pn[e]);
    }
#pragma unroll
    for (int e = 0; e < 8; ++e) {
      pn[e] += __shfl_xor(pn[e], 16);
      pn[e] += __shfl_xor(pn[e], 32);
    }
    if (kg == 0) {
      const float* srow = self0h + (size_t)n * OUT_F + dg * 8;  // already *0.5+out_bias
      float* orow = out + (size_t)n * OUT_F + dg * 8;
      f32x4 o0, o1;
#pragma unroll
      for (int e = 0; e < 4; ++e) o0[e] = fmaf(pn[e], scale2, srow[e]);
#pragma unroll
      for (int e = 0; e < 4; ++e) o1[e] = fmaf(pn[4 + e], scale2, srow[4 + e]);
      *(f32x4*)orow = o0;
      *(f32x4*)(orow + 4) = o1;
    }
  }
}

// ===========================================================================
// PATH B (fallback): exact R5 three-kernel pipeline (proven, 59.6 us)
// ===========================================================================
__global__ __launch_bounds__(256) void prep_kernel(
    const float* __restrict__ W_attn, const float* __restrict__ fW,
    const float* __restrict__ W_neigh, const float* __restrict__ W_self,
    float* __restrict__ w_comb, ushort* __restrict__ Bn, ushort* __restrict__ Bs) {
  const int b = blockIdx.x;
  const int t = threadIdx.x;
  if (b < 128) {
    __shared__ float red[256];
    float s = 0.f;
#pragma unroll
    for (int i = 0; i < 4; ++i) {
      int o = t + i * 256;
      s += W_attn[(size_t)b * ATTN_OUT + o] * fW[o];
    }
    red[t] = s;
    __syncthreads();
    for (int st = 128; st > 0; st >>= 1) {
      if (t < st) red[t] += red[t + st];
      __syncthreads();
    }
    if (t == 0) w_comb[b] = red[0];
  } else if (b < 256) {
    int k = 2 * (b - 128) + (t >> 7);
    int n = t & 127;
    Bn[(k >> 3) * 1024 + n * 8 + (k & 7)] = f2bf(W_neigh[(size_t)k * OUT_F + n]);
  } else {
    int k = 2 * (b - 256) + (t >> 7);
    int n = t & 127;
    Bs[(k >> 3) * 1024 + n * 8 + (k & 7)] = f2bf(W_self[(size_t)k * OUT_F + n]);
  }
}

__global__ __launch_bounds__(256, 4) void fused_gemm(
    const float* __restrict__ A,
    const ushort* __restrict__ Bn, const ushort* __restrict__ Bs,
    const float* __restrict__ bias_n, const float* __restrict__ bias_s,
    const float* __restrict__ w_comb, const float* __restrict__ out_bias,
    ushort* __restrict__ hsrc, float* __restrict__ self0, float* __restrict__ score_f) {
  if (blockIdx.x < NB_BIG)
    gemm_tile<true, true>(A, Bn, bias_n, out_bias, w_comb, score_f,
                          (void*)hsrc, N_SRC, blockIdx.x * 64);
  else
    gemm_tile<false, false>(A, Bs, bias_s, out_bias, nullptr, nullptr,
                            (void*)self0, N_DST, (blockIdx.x - NB_BIG) * 64);
}

__global__ __launch_bounds__(256, 4) void attn_kernel(
    const float* __restrict__ labels, const float* __restrict__ labels_ori,
    const float* __restrict__ label_rela, const int* __restrict__ nbr_idx,
    const ushort* __restrict__ hsrc, const float* __restrict__ self0,
    const float* __restrict__ score_f, const float* __restrict__ eps_p,
    const float* __restrict__ out_bias, float* __restrict__ out) {
  const int t = threadIdx.x;
  const int wv = t >> 6, ln = t & 63;
  const int n = blockIdx.x * 4 + wv;
  const int dg = ln & 15, kg = ln >> 4;

  const float eps = eps_p[0];
  const float om = 1.f - eps;

  float va = 0.f;
  if (dg < LDIM) {
#pragma unroll
    for (int b = 0; b < LDIM; ++b)
      va += label_rela[dg * LDIM + b] * labels[(size_t)n * LDIM + b];
    va *= eps;
  }

  const int* irow = nbr_idx + (size_t)n * KNBR;
  int ids[8];
  uint4 hv[8];
#pragma unroll
  for (int j = 0; j < 8; ++j) {
    ids[j] = irow[kg * 8 + j];
    hv[j] = *(const uint4*)(hsrc + (size_t)ids[j] * OUT_F + dg * 8);
  }
  float m[8];
#pragma unroll
  for (int j = 0; j < 8; ++j) {
    float sp = 0.f;
    if (dg == 0) sp = om * score_f[ids[j]];
    if (dg < LDIM) sp = fmaf(labels[(size_t)ids[j] * LDIM + dg], va, sp);
    m[j] = sp;
  }
#pragma unroll
  for (int s = 1; s < 16; s <<= 1) {
#pragma unroll
    for (int j = 0; j < 8; ++j) m[j] += __shfl_xor(m[j], s);
  }
  float mx = m[0];
#pragma unroll
  for (int j = 1; j < 8; ++j) mx = fmaxf(mx, m[j]);
  mx = fmaxf(mx, __shfl_xor(mx, 16));
  mx = fmaxf(mx, __shfl_xor(mx, 32));
  float ssum = 0.f;
#pragma unroll
  for (int j = 0; j < 8; ++j) {
    m[j] = __expf(m[j] - mx);
    ssum += m[j];
  }
  ssum += __shfl_xor(ssum, 16);
  ssum += __shfl_xor(ssum, 32);
  const float scale = 1.f / (ssum * (float)KNBR);
  float pn[8];
#pragma unroll
  for (int e = 0; e < 8; ++e) pn[e] = 0.f;
#pragma unroll
  for (int j = 0; j < 8; ++j) {
    float a = m[j];
    float hfj[8];
    unpack8(hv[j], hfj);
#pragma unroll
    for (int e = 0; e < 8; ++e) pn[e] = fmaf(a, hfj[e], pn[e]);
  }
#pragma unroll
  for (int e = 0; e < 8; ++e) {
    pn[e] += __shfl_xor(pn[e], 16);
    pn[e] += __shfl_xor(pn[e], 32);
  }
  if (kg == 0) {
    const float* srow = self0 + (size_t)n * OUT_F + dg * 8;  // pre-scaled
    float* orow = out + (size_t)n * OUT_F + dg * 8;
    f32x4 o0, o1;
#pragma unroll
    for (int e = 0; e < 4; ++e) o0[e] = fmaf(pn[e] * scale, 0.5f, srow[e]);
#pragma unroll
    for (int e = 0; e < 4; ++e) o1[e] = fmaf(pn[4 + e] * scale, 0.5f, srow[4 + e]);
    *(f32x4*)orow = o0;
    *(f32x4*)(orow + 4) = o1;
  }
  if (kg == 1 && dg < LDIM)
    out[OUT_CENT + (size_t)n * LDIM + dg] = labels[(size_t)n * LDIM + dg];
  if (kg == 2 && dg < LDIM)
    out[OUT_LORI + (size_t)n * LDIM + dg] = labels_ori[(size_t)n * LDIM + dg];
}

// ---------------------------------------------------------------------------
extern "C" void kernel_launch(void* const* d_in, const int* in_sizes, int n_in,
                              void* d_out, int out_size, void* d_ws, size_t ws_size,
                              hipStream_t stream) {
  const float* feat       = (const float*)d_in[0];
  const float* labels     = (const float*)d_in[1];
  const float* labels_ori = (const float*)d_in[2];
  const float* label_rela = (const float*)d_in[3];
  const float* W_neigh    = (const float*)d_in[4];
  const float* b_neigh    = (const float*)d_in[5];
  const float* W_self     = (const float*)d_in[6];
  const float* b_self     = (const float*)d_in[7];
  const float* W_attn     = (const float*)d_in[8];
  // d_in[9] = b_attn (constant under softmax -> unused)
  const float* fW         = (const float*)d_in[10];
  const float* eps        = (const float*)d_in[11];
  const float* out_bias   = (const float*)d_in[12];
  const int*   nbr_idx    = (const int*)d_in[13];

  float* wsf = (float*)d_ws;
  float* out = (float*)d_out;

  // Path A: cooperative, with occupancy-derived grid and checked launch.
  int bpc = 0;
  hipError_t oe = hipOccupancyMaxActiveBlocksPerMultiprocessor(
      &bpc, (const void*)fused_all, 256, 0);
  if (oe == hipSuccess && bpc >= 1) {
    int grid = (bpc >= 2 ? 2 : 1) * 256;
    void* args[] = {
        (void*)&feat, (void*)&labels, (void*)&labels_ori, (void*)&label_rela,
        (void*)&W_neigh, (void*)&b_neigh, (void*)&W_self, (void*)&b_self,
        (void*)&W_attn, (void*)&fW, (void*)&eps, (void*)&out_bias,
        (void*)&nbr_idx, (void*)&wsf, (void*)&out};
    hipError_t le = hipLaunchCooperativeKernel((const void*)fused_all,
                                               dim3(grid), dim3(256), args, 0, stream);
    if (le == hipSuccess) return;
    (void)hipGetLastError();  // clear sticky error before fallback
  } else {
    (void)hipGetLastError();
  }

  // Path B: proven three-kernel pipeline.
  float*  w_comb  = wsf + WS_WCOMB;
  ushort* Bn      = (ushort*)(wsf + WS_BN);
  ushort* Bsf     = (ushort*)(wsf + WS_BS);
  ushort* h_src   = (ushort*)(wsf + WS_HSRC);
  float*  self0   = wsf + WS_SELF0;
  float*  score_f = wsf + WS_SCORE;

  prep_kernel<<<384, 256, 0, stream>>>(W_attn, fW, W_neigh, W_self, w_comb, Bn, Bsf);
  fused_gemm<<<NB_BIG + NB_SELF, 256, 0, stream>>>(feat, Bn, Bsf, b_neigh, b_self,
                                                   w_comb, out_bias, h_src, self0, score_f);
  attn_kernel<<<(N_DST / 4), 256, 0, stream>>>(labels, labels_ori, label_rela, nbr_idx,
                                               h_src, self0, score_f, eps, out_bias, out);
}

// Round 8
// 62.195 us; speedup vs baseline: 3.8665x; 3.8665x over previous
//
#include <hip/hip_runtime.h>
#include <hip/hip_bf16.h>

#define N_SRC 50000
#define N_DST 10000
#define KNBR  32
#define IN_F  256
#define OUT_F 128
#define LDIM  10
#define ATTN_OUT 1024
#define NB2_BIG  1563   // ceil(50000/32)
#define NB2_SELF 313    // ceil(10000/32)
#define NB2_TOT  1876

using f32x4 = __attribute__((ext_vector_type(4))) float;
using s16x8 = __attribute__((ext_vector_type(8))) short;

// Output layout (floats): rst (N_DST*128) | cent_l (N_DST*10) | labels_ori[:N_DST] (N_DST*10)
#define OUT_CENT (N_DST*OUT_F)
#define OUT_LORI (N_DST*OUT_F + N_DST*LDIM)

// Workspace float offsets
#define WS_WCOMB 0                                   // 128 floats
#define WS_BN    128                                 // 32768 ushort
#define WS_BS    (128 + 16384)                       // 32768 ushort
#define WS_HSRC  (128 + 32768)                       // N_SRC*128 ushort
#define WS_SELF0 (WS_HSRC + (N_SRC*OUT_F/2))         // N_DST*128 floats (pre-scaled)
#define WS_SCORE (WS_SELF0 + N_DST*OUT_F)            // N_SRC floats

__device__ __forceinline__ ushort f2bf(float x) {
  __hip_bfloat16 h = __float2bfloat16(x);
  return *reinterpret_cast<ushort*>(&h);
}

__device__ __forceinline__ void unpack8(uint4 hv, float* o) {
  o[0] = __uint_as_float(hv.x << 16);
  o[1] = __uint_as_float(hv.x & 0xffff0000u);
  o[2] = __uint_as_float(hv.y << 16);
  o[3] = __uint_as_float(hv.y & 0xffff0000u);
  o[4] = __uint_as_float(hv.z << 16);
  o[5] = __uint_as_float(hv.z & 0xffff0000u);
  o[6] = __uint_as_float(hv.w << 16);
  o[7] = __uint_as_float(hv.w & 0xffff0000u);
}

// ---------------------------------------------------------------------------
// prep (R5 exact): blocks 0..127 w_comb | 128..255 W_neigh->bf16 | 256..383 W_self
// ---------------------------------------------------------------------------
__global__ __launch_bounds__(256) void prep_kernel(
    const float* __restrict__ W_attn, const float* __restrict__ fW,
    const float* __restrict__ W_neigh, const float* __restrict__ W_self,
    float* __restrict__ w_comb, ushort* __restrict__ Bn, ushort* __restrict__ Bs) {
  const int b = blockIdx.x;
  const int t = threadIdx.x;
  if (b < 128) {
    __shared__ float red[256];
    float s = 0.f;
#pragma unroll
    for (int i = 0; i < 4; ++i) {
      int o = t + i * 256;
      s += W_attn[(size_t)b * ATTN_OUT + o] * fW[o];
    }
    red[t] = s;
    __syncthreads();
    for (int st = 128; st > 0; st >>= 1) {
      if (t < st) red[t] += red[t + st];
      __syncthreads();
    }
    if (t == 0) w_comb[b] = red[0];
  } else if (b < 256) {
    int k = 2 * (b - 128) + (t >> 7);
    int n = t & 127;
    Bn[(k >> 3) * 1024 + n * 8 + (k & 7)] = f2bf(W_neigh[(size_t)k * OUT_F + n]);
  } else {
    int k = 2 * (b - 256) + (t >> 7);
    int n = t & 127;
    Bs[(k >> 3) * 1024 + n * 8 + (k & 7)] = f2bf(W_self[(size_t)k * OUT_F + n]);
  }
}

// ---------------------------------------------------------------------------
// K-split MFMA GEMM. Block = 32 rows = 2 groups x 16 rows; each group served
// by TWO waves (half=0: K 0..127, half=1: K 128..255). Per-wave chain is half
// of R5's (8 A-loads, 32 B-loads, 32 MFMAs, ~90 VGPR -> ~6 waves/SIMD).
// half-0 partials combined via 16 KB LDS; half-1 wave does the epilogue
// (+ per-row attention score for the NEIGH path).
// ---------------------------------------------------------------------------
template<bool NEIGH, bool SCORE>
__device__ __forceinline__ void gemm_tile_ks(
    const float* A, const ushort* Bp, const float* bias,
    const float* out_bias, const float* w_comb, float* score_f,
    void* C, int M, int m0) {
  __shared__ f32x4 lred[2][64][8];   // 16 KB
  const int t = threadIdx.x;
  const int wv = t >> 6, ln = t & 63;
  const int grp = wv >> 1, half = wv & 1;
  const int dg = ln & 15, kg = ln >> 4;
  int r = m0 + grp * 16 + dg;
  r = r < M ? r : M - 1;                    // branchless clamp: loads always valid
  const float* arow = &A[(size_t)r * IN_F + half * 128];

  // A: this wave's K-half for its row, 8 x 16B loads issued together.
  f32x4 araw[8];
#pragma unroll
  for (int k0 = 0; k0 < 4; ++k0) {
    const f32x4* ap = (const f32x4*)&arow[k0 * 32 + kg * 8];
    araw[2 * k0]     = ap[0];
    araw[2 * k0 + 1] = ap[1];
  }
  s16x8 afr[4];
#pragma unroll
  for (int k0 = 0; k0 < 4; ++k0) {
    s16x8 f;
    f[0] = (short)f2bf(araw[2*k0][0]); f[1] = (short)f2bf(araw[2*k0][1]);
    f[2] = (short)f2bf(araw[2*k0][2]); f[3] = (short)f2bf(araw[2*k0][3]);
    f[4] = (short)f2bf(araw[2*k0+1][0]); f[5] = (short)f2bf(araw[2*k0+1][1]);
    f[6] = (short)f2bf(araw[2*k0+1][2]); f[7] = (short)f2bf(araw[2*k0+1][3]);
    afr[k0] = f;
  }

  f32x4 acc[8];
#pragma unroll
  for (int ct = 0; ct < 8; ++ct) acc[ct] = (f32x4){0.f, 0.f, 0.f, 0.f};
#pragma unroll
  for (int k0 = 0; k0 < 4; ++k0) {
    const ushort* bb = Bp + (size_t)(half * 16 + k0 * 4 + kg) * 1024 + dg * 8;
#pragma unroll
    for (int ct = 0; ct < 8; ++ct) {
      s16x8 bfr = *reinterpret_cast<const s16x8*>(bb + ct * 128);
      acc[ct] = __builtin_amdgcn_mfma_f32_16x16x32_bf16(afr[k0], bfr, acc[ct], 0, 0, 0);
    }
  }

  // combine halves through LDS
  if (half == 0) {
#pragma unroll
    for (int ct = 0; ct < 8; ++ct) lred[grp][ln][ct] = acc[ct];
  }
  __syncthreads();
  if (half == 1) {
#pragma unroll
    for (int ct = 0; ct < 8; ++ct) {
      f32x4 o = lred[grp][ln][ct];
#pragma unroll
      for (int e = 0; e < 4; ++e) acc[ct][e] += o[e];
    }
    // Epilogue. D layout: col = ct*16+dg, row = m0+grp*16+kg*4+e (HW-verified m89).
    float sc[4] = {0.f, 0.f, 0.f, 0.f};
#pragma unroll
    for (int ct = 0; ct < 8; ++ct) {
      int col = ct * 16 + dg;
      float bb = bias[col];
      float wc = SCORE ? w_comb[col] : 0.f;
#pragma unroll
      for (int e = 0; e < 4; ++e) {
        int rr = m0 + grp * 16 + kg * 4 + e;
        float v = acc[ct][e] + bb;
        if (SCORE) sc[e] = fmaf(fmaxf(v, 0.1f * v), wc, sc[e]);
        if (rr < M) {
          if (NEIGH) ((ushort*)C)[(size_t)rr * OUT_F + col] = f2bf(v);
          else       ((float*)C)[(size_t)rr * OUT_F + col] = v * 0.5f + out_bias[col];
        }
      }
    }
    if (SCORE) {
#pragma unroll
      for (int s = 1; s < 16; s <<= 1) {
#pragma unroll
        for (int e = 0; e < 4; ++e) sc[e] += __shfl_xor(sc[e], s);
      }
      if (dg == 0) {
#pragma unroll
        for (int e = 0; e < 4; ++e) {
          int rr = m0 + grp * 16 + kg * 4 + e;
          if (rr < M) score_f[rr] = sc[e];
        }
      }
    }
  }
}

__global__ __launch_bounds__(256, 4) void fused_gemm(
    const float* __restrict__ A,
    const ushort* __restrict__ Bn, const ushort* __restrict__ Bs,
    const float* __restrict__ bias_n, const float* __restrict__ bias_s,
    const float* __restrict__ w_comb, const float* __restrict__ out_bias,
    ushort* __restrict__ hsrc, float* __restrict__ self0, float* __restrict__ score_f) {
  if (blockIdx.x < NB2_BIG)
    gemm_tile_ks<true, true>(A, Bn, bias_n, out_bias, w_comb, score_f,
                             (void*)hsrc, N_SRC, blockIdx.x * 32);
  else
    gemm_tile_ks<false, false>(A, Bs, bias_s, out_bias, nullptr, nullptr,
                               (void*)self0, N_DST, (blockIdx.x - NB2_BIG) * 32);
}

// ---------------------------------------------------------------------------
// attn (R5 structure): one wave per dst node, score gathered from score_f,
// packed h gathers feed only PV. self0 is pre-scaled (v*0.5+out_bias).
// ---------------------------------------------------------------------------
__global__ __launch_bounds__(256, 4) void attn_kernel(
    const float* __restrict__ labels, const float* __restrict__ labels_ori,
    const float* __restrict__ label_rela, const int* __restrict__ nbr_idx,
    const ushort* __restrict__ hsrc, const float* __restrict__ self0,
    const float* __restrict__ score_f, const float* __restrict__ eps_p,
    const float* __restrict__ out_bias, float* __restrict__ out) {
  const int t = threadIdx.x;
  const int wv = t >> 6, ln = t & 63;
  const int n = blockIdx.x * 4 + wv;
  const int dg = ln & 15, kg = ln >> 4;

  const float eps = eps_p[0];
  const float om = 1.f - eps;

  float va = 0.f;
  if (dg < LDIM) {
#pragma unroll
    for (int b = 0; b < LDIM; ++b)
      va += label_rela[dg * LDIM + b] * labels[(size_t)n * LDIM + b];
    va *= eps;
  }

  const int* irow = nbr_idx + (size_t)n * KNBR;
  int ids[8];
  uint4 hv[8];
#pragma unroll
  for (int j = 0; j < 8; ++j) {
    ids[j] = irow[kg * 8 + j];
    hv[j] = *(const uint4*)(hsrc + (size_t)ids[j] * OUT_F + dg * 8);
  }
  float m[8];
#pragma unroll
  for (int j = 0; j < 8; ++j) {
    float sp = 0.f;
    if (dg == 0) sp = om * score_f[ids[j]];
    if (dg < LDIM) sp = fmaf(labels[(size_t)ids[j] * LDIM + dg], va, sp);
    m[j] = sp;
  }
#pragma unroll
  for (int s = 1; s < 16; s <<= 1) {
#pragma unroll
    for (int j = 0; j < 8; ++j) m[j] += __shfl_xor(m[j], s);
  }
  float mx = m[0];
#pragma unroll
  for (int j = 1; j < 8; ++j) mx = fmaxf(mx, m[j]);
  mx = fmaxf(mx, __shfl_xor(mx, 16));
  mx = fmaxf(mx, __shfl_xor(mx, 32));
  float ssum = 0.f;
#pragma unroll
  for (int j = 0; j < 8; ++j) {
    m[j] = __expf(m[j] - mx);
    ssum += m[j];
  }
  ssum += __shfl_xor(ssum, 16);
  ssum += __shfl_xor(ssum, 32);
  const float scale2 = 0.5f / (ssum * (float)KNBR);   // folds rst*0.5 and mean/32
  float pn[8];
#pragma unroll
  for (int e = 0; e < 8; ++e) pn[e] = 0.f;
#pragma unroll
  for (int j = 0; j < 8; ++j) {
    float a = m[j];
    float hfj[8];
    unpack8(hv[j], hfj);
#pragma unroll
    for (int e = 0; e < 8; ++e) pn[e] = fmaf(a, hfj[e], pn[e]);
  }
#pragma unroll
  for (int e = 0; e < 8; ++e) {
    pn[e] += __shfl_xor(pn[e], 16);
    pn[e] += __shfl_xor(pn[e], 32);
  }
  if (kg == 0) {
    const float* srow = self0 + (size_t)n * OUT_F + dg * 8;  // pre-scaled
    float* orow = out + (size_t)n * OUT_F + dg * 8;
    f32x4 o0, o1;
#pragma unroll
    for (int e = 0; e < 4; ++e) o0[e] = fmaf(pn[e], scale2, srow[e]);
#pragma unroll
    for (int e = 0; e < 4; ++e) o1[e] = fmaf(pn[4 + e], scale2, srow[4 + e]);
    *(f32x4*)orow = o0;
    *(f32x4*)(orow + 4) = o1;
  }
  if (kg == 1 && dg < LDIM)
    out[OUT_CENT + (size_t)n * LDIM + dg] = labels[(size_t)n * LDIM + dg];
  if (kg == 2 && dg < LDIM)
    out[OUT_LORI + (size_t)n * LDIM + dg] = labels_ori[(size_t)n * LDIM + dg];
}

// ---------------------------------------------------------------------------
extern "C" void kernel_launch(void* const* d_in, const int* in_sizes, int n_in,
                              void* d_out, int out_size, void* d_ws, size_t ws_size,
                              hipStream_t stream) {
  const float* feat       = (const float*)d_in[0];
  const float* labels     = (const float*)d_in[1];
  const float* labels_ori = (const float*)d_in[2];
  const float* label_rela = (const float*)d_in[3];
  const float* W_neigh    = (const float*)d_in[4];
  const float* b_neigh    = (const float*)d_in[5];
  const float* W_self     = (const float*)d_in[6];
  const float* b_self     = (const float*)d_in[7];
  const float* W_attn     = (const float*)d_in[8];
  // d_in[9] = b_attn (constant under softmax -> unused)
  const float* fW         = (const float*)d_in[10];
  const float* eps        = (const float*)d_in[11];
  const float* out_bias   = (const float*)d_in[12];
  const int*   nbr_idx    = (const int*)d_in[13];

  float* wsf = (float*)d_ws;
  float* out = (float*)d_out;

  float*  w_comb  = wsf + WS_WCOMB;
  ushort* Bn      = (ushort*)(wsf + WS_BN);
  ushort* Bsf     = (ushort*)(wsf + WS_BS);
  ushort* h_src   = (ushort*)(wsf + WS_HSRC);
  float*  self0   = wsf + WS_SELF0;
  float*  score_f = wsf + WS_SCORE;

  prep_kernel<<<384, 256, 0, stream>>>(W_attn, fW, W_neigh, W_self, w_comb, Bn, Bsf);
  fused_gemm<<<NB2_TOT, 256, 0, stream>>>(feat, Bn, Bsf, b_neigh, b_self,
                                          w_comb, out_bias, h_src, self0, score_f);
  attn_kernel<<<(N_DST / 4), 256, 0, stream>>>(labels, labels_ori, label_rela, nbr_idx,
                                               h_src, self0, score_f, eps, out_bias, out);
}

// Round 9
// 62.195 us; speedup vs baseline: 3.8665x; 1.0000x over previous
//
#include <hip/hip_runtime.h>
#include <hip/hip_bf16.h>

#define N_SRC 50000
#define N_DST 10000
#define KNBR  32
#define IN_F  256
#define OUT_F 128
#define LDIM  10
#define ATTN_OUT 1024
#define NB2_BIG  1563   // ceil(50000/32)
#define NB2_SELF 313    // ceil(10000/32)
#define NB2_TOT  1876

using f32x4 = __attribute__((ext_vector_type(4))) float;
using s16x8 = __attribute__((ext_vector_type(8))) short;

// Output layout (floats): rst (N_DST*128) | cent_l (N_DST*10) | labels_ori[:N_DST] (N_DST*10)
#define OUT_CENT (N_DST*OUT_F)
#define OUT_LORI (N_DST*OUT_F + N_DST*LDIM)

// Workspace float offsets
#define WS_WCOMB 0                                   // 128 floats
#define WS_BN    128                                 // 32768 ushort
#define WS_BS    (128 + 16384)                       // 32768 ushort
#define WS_HSRC  (128 + 32768)                       // N_SRC*128 ushort
#define WS_SELF0 (WS_HSRC + (N_SRC*OUT_F/2))         // N_DST*128 floats (pre-scaled)
#define WS_SCORE (WS_SELF0 + N_DST*OUT_F)            // N_SRC floats

__device__ __forceinline__ ushort f2bf(float x) {
  __hip_bfloat16 h = __float2bfloat16(x);
  return *reinterpret_cast<ushort*>(&h);
}

__device__ __forceinline__ void unpack8(uint4 hv, float* o) {
  o[0] = __uint_as_float(hv.x << 16);
  o[1] = __uint_as_float(hv.x & 0xffff0000u);
  o[2] = __uint_as_float(hv.y << 16);
  o[3] = __uint_as_float(hv.y & 0xffff0000u);
  o[4] = __uint_as_float(hv.z << 16);
  o[5] = __uint_as_float(hv.z & 0xffff0000u);
  o[6] = __uint_as_float(hv.w << 16);
  o[7] = __uint_as_float(hv.w & 0xffff0000u);
}

// ---------------------------------------------------------------------------
// prep (R5 exact): blocks 0..127 w_comb | 128..255 W_neigh->bf16 | 256..383 W_self
// ---------------------------------------------------------------------------
__global__ __launch_bounds__(256) void prep_kernel(
    const float* __restrict__ W_attn, const float* __restrict__ fW,
    const float* __restrict__ W_neigh, const float* __restrict__ W_self,
    float* __restrict__ w_comb, ushort* __restrict__ Bn, ushort* __restrict__ Bs) {
  const int b = blockIdx.x;
  const int t = threadIdx.x;
  if (b < 128) {
    __shared__ float red[256];
    float s = 0.f;
#pragma unroll
    for (int i = 0; i < 4; ++i) {
      int o = t + i * 256;
      s += W_attn[(size_t)b * ATTN_OUT + o] * fW[o];
    }
    red[t] = s;
    __syncthreads();
    for (int st = 128; st > 0; st >>= 1) {
      if (t < st) red[t] += red[t + st];
      __syncthreads();
    }
    if (t == 0) w_comb[b] = red[0];
  } else if (b < 256) {
    int k = 2 * (b - 128) + (t >> 7);
    int n = t & 127;
    Bn[(k >> 3) * 1024 + n * 8 + (k & 7)] = f2bf(W_neigh[(size_t)k * OUT_F + n]);
  } else {
    int k = 2 * (b - 256) + (t >> 7);
    int n = t & 127;
    Bs[(k >> 3) * 1024 + n * 8 + (k & 7)] = f2bf(W_self[(size_t)k * OUT_F + n]);
  }
}

// ---------------------------------------------------------------------------
// K-split MFMA GEMM. Block = 32 rows = 2 groups x 16 rows; each group served
// by TWO waves (half=0: K 0..127, half=1: K 128..255). Per-wave chain is half
// of R5's (8 A-loads, 32 B-loads, 32 MFMAs, ~90 VGPR -> ~6 waves/SIMD).
// half-0 partials combined via 16 KB LDS; half-1 wave does the epilogue
// (+ per-row attention score for the NEIGH path).
// ---------------------------------------------------------------------------
template<bool NEIGH, bool SCORE>
__device__ __forceinline__ void gemm_tile_ks(
    const float* A, const ushort* Bp, const float* bias,
    const float* out_bias, const float* w_comb, float* score_f,
    void* C, int M, int m0) {
  __shared__ f32x4 lred[2][64][8];   // 16 KB
  const int t = threadIdx.x;
  const int wv = t >> 6, ln = t & 63;
  const int grp = wv >> 1, half = wv & 1;
  const int dg = ln & 15, kg = ln >> 4;
  int r = m0 + grp * 16 + dg;
  r = r < M ? r : M - 1;                    // branchless clamp: loads always valid
  const float* arow = &A[(size_t)r * IN_F + half * 128];

  // A: this wave's K-half for its row, 8 x 16B loads issued together.
  f32x4 araw[8];
#pragma unroll
  for (int k0 = 0; k0 < 4; ++k0) {
    const f32x4* ap = (const f32x4*)&arow[k0 * 32 + kg * 8];
    araw[2 * k0]     = ap[0];
    araw[2 * k0 + 1] = ap[1];
  }
  s16x8 afr[4];
#pragma unroll
  for (int k0 = 0; k0 < 4; ++k0) {
    s16x8 f;
    f[0] = (short)f2bf(araw[2*k0][0]); f[1] = (short)f2bf(araw[2*k0][1]);
    f[2] = (short)f2bf(araw[2*k0][2]); f[3] = (short)f2bf(araw[2*k0][3]);
    f[4] = (short)f2bf(araw[2*k0+1][0]); f[5] = (short)f2bf(araw[2*k0+1][1]);
    f[6] = (short)f2bf(araw[2*k0+1][2]); f[7] = (short)f2bf(araw[2*k0+1][3]);
    afr[k0] = f;
  }

  f32x4 acc[8];
#pragma unroll
  for (int ct = 0; ct < 8; ++ct) acc[ct] = (f32x4){0.f, 0.f, 0.f, 0.f};
#pragma unroll
  for (int k0 = 0; k0 < 4; ++k0) {
    const ushort* bb = Bp + (size_t)(half * 16 + k0 * 4 + kg) * 1024 + dg * 8;
#pragma unroll
    for (int ct = 0; ct < 8; ++ct) {
      s16x8 bfr = *reinterpret_cast<const s16x8*>(bb + ct * 128);
      acc[ct] = __builtin_amdgcn_mfma_f32_16x16x32_bf16(afr[k0], bfr, acc[ct], 0, 0, 0);
    }
  }

  // combine halves through LDS
  if (half == 0) {
#pragma unroll
    for (int ct = 0; ct < 8; ++ct) lred[grp][ln][ct] = acc[ct];
  }
  __syncthreads();
  if (half == 1) {
#pragma unroll
    for (int ct = 0; ct < 8; ++ct) {
      f32x4 o = lred[grp][ln][ct];
#pragma unroll
      for (int e = 0; e < 4; ++e) acc[ct][e] += o[e];
    }
    // Epilogue. D layout: col = ct*16+dg, row = m0+grp*16+kg*4+e (HW-verified m89).
    float sc[4] = {0.f, 0.f, 0.f, 0.f};
#pragma unroll
    for (int ct = 0; ct < 8; ++ct) {
      int col = ct * 16 + dg;
      float bb = bias[col];
      float wc = SCORE ? w_comb[col] : 0.f;
#pragma unroll
      for (int e = 0; e < 4; ++e) {
        int rr = m0 + grp * 16 + kg * 4 + e;
        float v = acc[ct][e] + bb;
        if (SCORE) sc[e] = fmaf(fmaxf(v, 0.1f * v), wc, sc[e]);
        if (rr < M) {
          if (NEIGH) ((ushort*)C)[(size_t)rr * OUT_F + col] = f2bf(v);
          else       ((float*)C)[(size_t)rr * OUT_F + col] = v * 0.5f + out_bias[col];
        }
      }
    }
    if (SCORE) {
#pragma unroll
      for (int s = 1; s < 16; s <<= 1) {
#pragma unroll
        for (int e = 0; e < 4; ++e) sc[e] += __shfl_xor(sc[e], s);
      }
      if (dg == 0) {
#pragma unroll
        for (int e = 0; e < 4; ++e) {
          int rr = m0 + grp * 16 + kg * 4 + e;
          if (rr < M) score_f[rr] = sc[e];
        }
      }
    }
  }
}

__global__ __launch_bounds__(256, 4) void fused_gemm(
    const float* __restrict__ A,
    const ushort* __restrict__ Bn, const ushort* __restrict__ Bs,
    const float* __restrict__ bias_n, const float* __restrict__ bias_s,
    const float* __restrict__ w_comb, const float* __restrict__ out_bias,
    ushort* __restrict__ hsrc, float* __restrict__ self0, float* __restrict__ score_f) {
  if (blockIdx.x < NB2_BIG)
    gemm_tile_ks<true, true>(A, Bn, bias_n, out_bias, w_comb, score_f,
                             (void*)hsrc, N_SRC, blockIdx.x * 32);
  else
    gemm_tile_ks<false, false>(A, Bs, bias_s, out_bias, nullptr, nullptr,
                               (void*)self0, N_DST, (blockIdx.x - NB2_BIG) * 32);
}

// ---------------------------------------------------------------------------
// attn (R5 structure): one wave per dst node, score gathered from score_f,
// packed h gathers feed only PV. self0 is pre-scaled (v*0.5+out_bias).
// ---------------------------------------------------------------------------
__global__ __launch_bounds__(256, 4) void attn_kernel(
    const float* __restrict__ labels, const float* __restrict__ labels_ori,
    const float* __restrict__ label_rela, const int* __restrict__ nbr_idx,
    const ushort* __restrict__ hsrc, const float* __restrict__ self0,
    const float* __restrict__ score_f, const float* __restrict__ eps_p,
    const float* __restrict__ out_bias, float* __restrict__ out) {
  const int t = threadIdx.x;
  const int wv = t >> 6, ln = t & 63;
  const int n = blockIdx.x * 4 + wv;
  const int dg = ln & 15, kg = ln >> 4;

  const float eps = eps_p[0];
  const float om = 1.f - eps;

  float va = 0.f;
  if (dg < LDIM) {
#pragma unroll
    for (int b = 0; b < LDIM; ++b)
      va += label_rela[dg * LDIM + b] * labels[(size_t)n * LDIM + b];
    va *= eps;
  }

  const int* irow = nbr_idx + (size_t)n * KNBR;
  int ids[8];
  uint4 hv[8];
#pragma unroll
  for (int j = 0; j < 8; ++j) {
    ids[j] = irow[kg * 8 + j];
    hv[j] = *(const uint4*)(hsrc + (size_t)ids[j] * OUT_F + dg * 8);
  }
  float m[8];
#pragma unroll
  for (int j = 0; j < 8; ++j) {
    float sp = 0.f;
    if (dg == 0) sp = om * score_f[ids[j]];
    if (dg < LDIM) sp = fmaf(labels[(size_t)ids[j] * LDIM + dg], va, sp);
    m[j] = sp;
  }
#pragma unroll
  for (int s = 1; s < 16; s <<= 1) {
#pragma unroll
    for (int j = 0; j < 8; ++j) m[j] += __shfl_xor(m[j], s);
  }
  float mx = m[0];
#pragma unroll
  for (int j = 1; j < 8; ++j) mx = fmaxf(mx, m[j]);
  mx = fmaxf(mx, __shfl_xor(mx, 16));
  mx = fmaxf(mx, __shfl_xor(mx, 32));
  float ssum = 0.f;
#pragma unroll
  for (int j = 0; j < 8; ++j) {
    m[j] = __expf(m[j] - mx);
    ssum += m[j];
  }
  ssum += __shfl_xor(ssum, 16);
  ssum += __shfl_xor(ssum, 32);
  const float scale2 = 0.5f / (ssum * (float)KNBR);   // folds rst*0.5 and mean/32
  float pn[8];
#pragma unroll
  for (int e = 0; e < 8; ++e) pn[e] = 0.f;
#pragma unroll
  for (int j = 0; j < 8; ++j) {
    float a = m[j];
    float hfj[8];
    unpack8(hv[j], hfj);
#pragma unroll
    for (int e = 0; e < 8; ++e) pn[e] = fmaf(a, hfj[e], pn[e]);
  }
#pragma unroll
  for (int e = 0; e < 8; ++e) {
    pn[e] += __shfl_xor(pn[e], 16);
    pn[e] += __shfl_xor(pn[e], 32);
  }
  if (kg == 0) {
    const float* srow = self0 + (size_t)n * OUT_F + dg * 8;  // pre-scaled
    float* orow = out + (size_t)n * OUT_F + dg * 8;
    f32x4 o0, o1;
#pragma unroll
    for (int e = 0; e < 4; ++e) o0[e] = fmaf(pn[e], scale2, srow[e]);
#pragma unroll
    for (int e = 0; e < 4; ++e) o1[e] = fmaf(pn[4 + e], scale2, srow[4 + e]);
    *(f32x4*)orow = o0;
    *(f32x4*)(orow + 4) = o1;
  }
  if (kg == 1 && dg < LDIM)
    out[OUT_CENT + (size_t)n * LDIM + dg] = labels[(size_t)n * LDIM + dg];
  if (kg == 2 && dg < LDIM)
    out[OUT_LORI + (size_t)n * LDIM + dg] = labels_ori[(size_t)n * LDIM + dg];
}

// ---------------------------------------------------------------------------
extern "C" void kernel_launch(void* const* d_in, const int* in_sizes, int n_in,
                              void* d_out, int out_size, void* d_ws, size_t ws_size,
                              hipStream_t stream) {
  const float* feat       = (const float*)d_in[0];
  const float* labels     = (const float*)d_in[1];
  const float* labels_ori = (const float*)d_in[2];
  const float* label_rela = (const float*)d_in[3];
  const float* W_neigh    = (const float*)d_in[4];
  const float* b_neigh    = (const float*)d_in[5];
  const float* W_self     = (const float*)d_in[6];
  const float* b_self     = (const float*)d_in[7];
  const float* W_attn     = (const float*)d_in[8];
  // d_in[9] = b_attn (constant under softmax -> unused)
  const float* fW         = (const float*)d_in[10];
  const float* eps        = (const float*)d_in[11];
  const float* out_bias   = (const float*)d_in[12];
  const int*   nbr_idx    = (const int*)d_in[13];

  float* wsf = (float*)d_ws;
  float* out = (float*)d_out;

  float*  w_comb  = wsf + WS_WCOMB;
  ushort* Bn      = (ushort*)(wsf + WS_BN);
  ushort* Bsf     = (ushort*)(wsf + WS_BS);
  ushort* h_src   = (ushort*)(wsf + WS_HSRC);
  float*  self0   = wsf + WS_SELF0;
  float*  score_f = wsf + WS_SCORE;

  prep_kernel<<<384, 256, 0, stream>>>(W_attn, fW, W_neigh, W_self, w_comb, Bn, Bsf);
  fused_gemm<<<NB2_TOT, 256, 0, stream>>>(feat, Bn, Bsf, b_neigh, b_self,
                                          w_comb, out_bias, h_src, self0, score_f);
  attn_kernel<<<(N_DST / 4), 256, 0, stream>>>(labels, labels_ori, label_rela, nbr_idx,
                                               h_src, self0, score_f, eps, out_bias, out);
}